// Round 11
// baseline (1453.211 us; speedup 1.0000x reference)
//
#include <hip/hip_runtime.h>

// 2-layer stacked LSTM (shared cell), B=256, T=1024, F=UNITS=128 — MFMA v8.
// = v5 (round 7, 1102us) + wave-parity ANTI-PHASED schedules:
//   even waves: v5 schedule (g,o chains -> i,f chains w/ g,o-trans spliced
//               -> sigma(i,f) tail)
//   odd waves:  all 32 MFMAs contiguously (ILP2) -> all trans as a block
// The two SIMD-mate waves are now at different phase types at any time, so
// the MFMA pipe is fed by one wave while the other issues transcendentals
// (a wave64 trans op blocks its wave's issue slot ~8cyc; in v5 both waves
// hit trans regions simultaneously -> pipe starvation).
//
// 32 LSTM WGs (512 thr, 8 waves) x 8 batch rows (full M=16 = 8 batch x 2
// cells); blocks 32..255 fill the zeros output.
// Per tick k: acc = A1@W + A2@U, A1 = rows 0-15 [x(k); h1(k-1)],
// A2 = rows 8-23 [h1(k-1); h2(k-2)]. acc rows 0-7 = z1 (cell1 step k),
// rows 8-15 = z2 (cell2 step k-1). Epilogue acc-lane-local; lanes lc<2 run
// cell1, lc>=2 run cell2. One barrier per tick.
//
// d_out (f32): [0,32768) h2_final | [32768,+33554432) zeros | [33587200,..) c1

typedef _Float16 f16;
typedef _Float16 f16x2 __attribute__((ext_vector_type(2)));
typedef _Float16 f16x8 __attribute__((ext_vector_type(8)));
typedef float    f32x4 __attribute__((ext_vector_type(4)));

#define T_STEPS 1024
#define UNITS   128
#define NLSTM   32
#define BPW     8
#define NBLK    256
#define OUT_ZERO 32768
#define OUT_C1   33587200
#define BUFB    6144   // 24 rows * 256B (x:0-7, h1:8-15, h2:16-23)

#define MFMA16(A, B, C) __builtin_amdgcn_mfma_f32_16x16x32_f16((A), (B), (C), 0, 0, 0)

__device__ __forceinline__ float frcp_(float x) {
#if __has_builtin(__builtin_amdgcn_rcpf)
    return __builtin_amdgcn_rcpf(x);
#else
    return 1.0f / x;
#endif
}
__device__ __forceinline__ float sigmoidf_(float x) {
    return frcp_(1.0f + __expf(-x));
}
__device__ __forceinline__ float tanhf_(float x) {
    float e = __expf(2.0f * x);
    return 1.0f - 2.0f * frcp_(e + 1.0f);
}
__device__ __forceinline__ unsigned pkh(float a, float b) {
    f16x2 t; t[0] = (f16)a; t[1] = (f16)b;
    return __builtin_bit_cast(unsigned, t);
}

__global__ __launch_bounds__(512, 2) void lstm2_kernel(
    const float* __restrict__ X,   // [256][1024][128]
    const float* __restrict__ W,   // [128][512] gate order i|f|g|o
    const float* __restrict__ U,   // [128][512]
    const float* __restrict__ Bv,  // [512]
    float* __restrict__ out)
{
    const int blk = blockIdx.x;
    const int tid = threadIdx.x;

    if (blk >= NLSTM) {
        // ---------- zeros-output fill on idle CUs ----------
        const size_t nthr = (size_t)(NBLK - NLSTM) * 512;
        float4* dst = (float4*)(out + OUT_ZERO);
        const float4 z4 = make_float4(0.f, 0.f, 0.f, 0.f);
        for (size_t i = (size_t)(blk - NLSTM) * 512 + tid; i < 8388608u; i += nthr)
            dst[i] = z4;
        return;
    }

    // ---------- LSTM workgroup ----------
    const int w  = tid >> 6;        // wave = unit block [16w,16w+16)
    const int l  = tid & 63;
    const int lr = l & 15;          // A row / C col (unit within block)
    const int lc = l >> 4;          // k-chunk / C row group
    const int u  = w * 16 + lr;     // unit in [0,128)
    const int b0 = blk * BPW;
    const bool cell2 = (l >= 32);

    __shared__ __align__(16) char Abuf[2][BUFB];
    char* Ab = (char*)Abuf;

    // ---- weight B-fragments (resident): [gate][ktile], 8 f16 each
    f16x8 Wf[4][4], Uf[4][4];
    #pragma unroll
    for (int g = 0; g < 4; ++g) {
        #pragma unroll
        for (int kt = 0; kt < 4; ++kt) {
            f16x8 wt, ut;
            #pragma unroll
            for (int j = 0; j < 8; ++j) {
                const int krow = kt * 32 + lc * 8 + j;
                wt[j] = (f16)W[(size_t)krow * 512 + g * 128 + u];
                ut[j] = (f16)U[(size_t)krow * 512 + g * 128 + u];
            }
            Wf[g][kt] = wt;  Uf[g][kt] = ut;
        }
    }
    float bias[4];
    #pragma unroll
    for (int g = 0; g < 4; ++g) bias[g] = Bv[g * 128 + u];

    // ---- precomputed swizzled addresses (lane constants)
    const int swz = (lr & 7) << 4;
    int raddr[2][4];
    #pragma unroll
    for (int a0 = 0; a0 < 2; ++a0)
        #pragma unroll
        for (int kt = 0; kt < 4; ++kt)
            raddr[a0][kt] = (((a0 * 8 + lr) * 256) + kt * 64 + lc * 16) ^ swz;
    int waddr[4];
    #pragma unroll
    for (int e = 0; e < 4; ++e)
        waddr[e] = ((8 + 4 * lc + e) * 256 + u * 2) ^ ((((4 * lc + e) & 7)) << 4);

    // ---- init LDS: zero both buffers, load x[0] into buf0 rows 0-7
    for (int i = tid; i < 3072; i += 512) ((float*)Ab)[i] = 0.0f;
    {
        const int flat = tid * 2, xr = flat >> 7, xc = flat & 127;
        const float2 xv = *(const float2*)(X + (size_t)(b0 + xr) * (T_STEPS * UNITS) + xc);
        const int byte = ((xr * 256 + xc * 2) ^ ((xr & 7) << 4));
        *(unsigned*)(Ab + byte) = pkh(xv.x, xv.y);
    }
    __syncthreads();

    float cst[4] = {0.f, 0.f, 0.f, 0.f};   // c1 (lanes<32) / c2 (lanes>=32)

    for (int k = 0; k <= T_STEPS; ++k) {
        const int rdo = (k & 1) * BUFB, wro = BUFB - rdo;

        // issue x[k+1] prefetch early (hides HBM latency under MFMA phase)
        float xa = 0.f, xb = 0.f; int xr = 0, xc = 0;
        if (k + 1 < T_STEPS) {
            const int flat = tid * 2; xr = flat >> 7; xc = flat & 127;
            const float2 xv = *(const float2*)(X + (size_t)(b0 + xr) * (T_STEPS * UNITS)
                                                 + (size_t)(k + 1) * UNITS + xc);
            xa = xv.x; xb = xv.y;
        }
        const int xbyte = ((xr * 256 + xc * 2) ^ ((xr & 7) << 4));

        // ---- A fragments from LDS
        f16x8 A1[4], A2[4];
        #pragma unroll
        for (int kt = 0; kt < 4; ++kt) {
            A1[kt] = *(const f16x8*)(Ab + rdo + raddr[0][kt]);
            A2[kt] = *(const f16x8*)(Ab + rdo + raddr[1][kt]);
        }

        float gg[4], oo[4], si[4], sf[4];

        if ((w & 1) == 0) {
            // ========== EVEN wave: v5 schedule ==========
            // P1: g,o chains (16 MFMA, ILP2)
            f32x4 accg = {bias[2], bias[2], bias[2], bias[2]};
            f32x4 acco = {bias[3], bias[3], bias[3], bias[3]};
            #pragma unroll
            for (int kt = 0; kt < 4; ++kt) {
                accg = MFMA16(A1[kt], Wf[2][kt], accg);
                acco = MFMA16(A1[kt], Wf[3][kt], acco);
            }
            #pragma unroll
            for (int kt = 0; kt < 4; ++kt) {
                accg = MFMA16(A2[kt], Uf[2][kt], accg);
                acco = MFMA16(A2[kt], Uf[3][kt], acco);
            }
            // P2: i,f chains with g/o trans spliced
            f32x4 acci = {bias[0], bias[0], bias[0], bias[0]};
            f32x4 accf = {bias[1], bias[1], bias[1], bias[1]};
            acci = MFMA16(A1[0], Wf[0][0], acci);  accf = MFMA16(A1[0], Wf[1][0], accf);
            gg[0] = tanhf_(accg[0]);
            acci = MFMA16(A1[1], Wf[0][1], acci);  accf = MFMA16(A1[1], Wf[1][1], accf);
            oo[0] = sigmoidf_(acco[0]);
            acci = MFMA16(A1[2], Wf[0][2], acci);  accf = MFMA16(A1[2], Wf[1][2], accf);
            gg[1] = tanhf_(accg[1]);
            acci = MFMA16(A1[3], Wf[0][3], acci);  accf = MFMA16(A1[3], Wf[1][3], accf);
            oo[1] = sigmoidf_(acco[1]);
            acci = MFMA16(A2[0], Uf[0][0], acci);  accf = MFMA16(A2[0], Uf[1][0], accf);
            gg[2] = tanhf_(accg[2]);
            if (k + 1 < T_STEPS)   // x(k+1) -> write buffer rows 0-7
                *(unsigned*)(Ab + wro + xbyte) = pkh(xa, xb);
            acci = MFMA16(A2[1], Uf[0][1], acci);  accf = MFMA16(A2[1], Uf[1][1], accf);
            oo[2] = sigmoidf_(acco[2]);
            acci = MFMA16(A2[2], Uf[0][2], acci);  accf = MFMA16(A2[2], Uf[1][2], accf);
            gg[3] = tanhf_(accg[3]);
            acci = MFMA16(A2[3], Uf[0][3], acci);  accf = MFMA16(A2[3], Uf[1][3], accf);
            oo[3] = sigmoidf_(acco[3]);
            // tail trans: sigma(i), sigma(f)
            #pragma unroll
            for (int e = 0; e < 4; ++e) {
                si[e] = sigmoidf_(acci[e]);
                sf[e] = sigmoidf_(accf[e]);
            }
        } else {
            // ========== ODD wave: 32 contiguous MFMAs, then trans block ==========
            f32x4 acci = {bias[0], bias[0], bias[0], bias[0]};
            f32x4 accf = {bias[1], bias[1], bias[1], bias[1]};
            #pragma unroll
            for (int kt = 0; kt < 4; ++kt) {
                acci = MFMA16(A1[kt], Wf[0][kt], acci);
                accf = MFMA16(A1[kt], Wf[1][kt], accf);
            }
            #pragma unroll
            for (int kt = 0; kt < 4; ++kt) {
                acci = MFMA16(A2[kt], Uf[0][kt], acci);
                accf = MFMA16(A2[kt], Uf[1][kt], accf);
            }
            f32x4 accg = {bias[2], bias[2], bias[2], bias[2]};
            f32x4 acco = {bias[3], bias[3], bias[3], bias[3]};
            #pragma unroll
            for (int kt = 0; kt < 4; ++kt) {
                accg = MFMA16(A1[kt], Wf[2][kt], accg);
                acco = MFMA16(A1[kt], Wf[3][kt], acco);
            }
            #pragma unroll
            for (int kt = 0; kt < 4; ++kt) {
                accg = MFMA16(A2[kt], Uf[2][kt], accg);
                acco = MFMA16(A2[kt], Uf[3][kt], acco);
            }
            if (k + 1 < T_STEPS)   // x(k+1) -> write buffer rows 0-7
                *(unsigned*)(Ab + wro + xbyte) = pkh(xa, xb);
            // trans block (overlaps even waves' P2/P3 MFMAs)
            #pragma unroll
            for (int e = 0; e < 4; ++e) {
                si[e] = sigmoidf_(acci[e]);
                sf[e] = sigmoidf_(accf[e]);
                gg[e] = tanhf_(accg[e]);
                oo[e] = sigmoidf_(acco[e]);
            }
        }

        // ---- common tail: c update + tanh(c) + h writes
        const bool active = cell2 ? (k > 0) : (k < T_STEPS);
        const bool wact = active && (k < T_STEPS);
        float hq[4];
        #pragma unroll
        for (int e = 0; e < 4; ++e) {
            const float cn = sf[e] * cst[e] + si[e] * gg[e];
            if (active) cst[e] = cn;
            hq[e] = oo[e] * tanhf_(cn);
            if (wact)
                *(f16*)(Ab + wro + waddr[e]) = (f16)hq[e];
        }

        // ---- final outputs
        if (k == T_STEPS - 1 && !cell2) {
            #pragma unroll
            for (int e = 0; e < 4; ++e)
                out[OUT_C1 + (size_t)(b0 + 4 * lc + e) * UNITS + u] = cst[e];
        }
        if (k == T_STEPS && cell2) {
            #pragma unroll
            for (int e = 0; e < 4; ++e)
                out[(size_t)(b0 + 4 * lc + e - 8) * UNITS + u] = hq[e];
        }
        __syncthreads();
    }
}

extern "C" void kernel_launch(void* const* d_in, const int* in_sizes, int n_in,
                              void* d_out, int out_size, void* d_ws, size_t ws_size,
                              hipStream_t stream) {
    const float* X  = (const float*)d_in[0];
    const float* W  = (const float*)d_in[1];
    const float* U  = (const float*)d_in[2];
    const float* Bv = (const float*)d_in[3];
    float* out = (float*)d_out;
    hipLaunchKernelGGL(lstm2_kernel, dim3(NBLK), dim3(512), 0, stream,
                       X, W, U, Bv, out);
}

// Round 12
// 996.854 us; speedup vs baseline: 1.4578x; 1.4578x over previous
//
#include <hip/hip_runtime.h>

// 2-layer stacked LSTM (shared cell), B=256, T=1024, F=UNITS=128 — MFMA v9.
// 64 LSTM WGs (512 thr, 8 waves) x 4 batch rows; blocks 64..255 fill zeros.
//
// Cell-interleaved M layout (the fix over round 4's failed BPW=4):
//   A1 row 4a   = x_a(k)     A2 row 4a   = h1_a(k-1)   -> z1 batch a (e=0)
//   A1 row 4a+1 = h1_a(k-1)  A2 row 4a+1 = h2_a(k-2)   -> z2 batch a (e=1)
//   rows 4a+2,3 = zero pad (never written, acc discarded)
// acc row = 4*lc + e  =>  every lane owns batch lc: e=0 cell1, e=1 cell2.
// Trans ops/wave/tick: 20 (vs 40 at BPW=8) — per-CU matrix cost unchanged
// (256 MFMA/WG/tick is M-independent), so doubling CUs halves the epilogue
// roof. No repack/zlds/extra barrier needed. Schedule = v5's proven splice:
// g,o chains -> i,f chains with tanh(g)/sigma(o) + x-write spliced -> tail.
//
// d_out (f32): [0,32768) h2_final | [32768,+33554432) zeros | [33587200,..) c1

typedef _Float16 f16;
typedef _Float16 f16x2 __attribute__((ext_vector_type(2)));
typedef _Float16 f16x8 __attribute__((ext_vector_type(8)));
typedef float    f32x4 __attribute__((ext_vector_type(4)));

#define T_STEPS 1024
#define UNITS   128
#define NLSTM   64
#define BPW     4
#define NBLK    256
#define OUT_ZERO 32768
#define OUT_C1   33587200
#define TILEB   4096   // 16 rows * 256B per A-tile

#define MFMA16(A, B, C) __builtin_amdgcn_mfma_f32_16x16x32_f16((A), (B), (C), 0, 0, 0)

__device__ __forceinline__ float frcp_(float x) {
#if __has_builtin(__builtin_amdgcn_rcpf)
    return __builtin_amdgcn_rcpf(x);
#else
    return 1.0f / x;
#endif
}
__device__ __forceinline__ float sigmoidf_(float x) {
    return frcp_(1.0f + __expf(-x));
}
__device__ __forceinline__ float tanhf_(float x) {
    float e = __expf(2.0f * x);
    return 1.0f - 2.0f * frcp_(e + 1.0f);
}
__device__ __forceinline__ unsigned pkh(float a, float b) {
    f16x2 t; t[0] = (f16)a; t[1] = (f16)b;
    return __builtin_bit_cast(unsigned, t);
}
// swizzled byte address within a 16-row x 256B tile (XOR 16B slot by row&7)
__device__ __forceinline__ int swb(int row, int byteoff) {
    return row * 256 + (byteoff ^ ((row & 7) << 4));
}

__global__ __launch_bounds__(512, 2) void lstm2_kernel(
    const float* __restrict__ X,   // [256][1024][128]
    const float* __restrict__ W,   // [128][512] gate order i|f|g|o
    const float* __restrict__ U,   // [128][512]
    const float* __restrict__ Bv,  // [512]
    float* __restrict__ out)
{
    const int blk = blockIdx.x;
    const int tid = threadIdx.x;

    if (blk >= NLSTM) {
        // ---------- zeros-output fill on idle CUs ----------
        const size_t nthr = (size_t)(NBLK - NLSTM) * 512;
        float4* dst = (float4*)(out + OUT_ZERO);
        const float4 z4 = make_float4(0.f, 0.f, 0.f, 0.f);
        for (size_t i = (size_t)(blk - NLSTM) * 512 + tid; i < 8388608u; i += nthr)
            dst[i] = z4;
        return;
    }

    // ---------- LSTM workgroup ----------
    const int w  = tid >> 6;        // wave = unit block [16w,16w+16)
    const int l  = tid & 63;
    const int lr = l & 15;          // A row-in-tile / C col (unit in block)
    const int lc = l >> 4;          // k-sub / batch row owned
    const int u  = w * 16 + lr;     // unit in [0,128)
    const int b0 = blk * BPW;

    __shared__ __align__(16) char A1b[2][TILEB];
    __shared__ __align__(16) char A2b[2][TILEB];

    // ---- weight B-fragments (resident): [gate][ktile], 8 f16 each
    f16x8 Wf[4][4], Uf[4][4];
    #pragma unroll
    for (int g = 0; g < 4; ++g) {
        #pragma unroll
        for (int kt = 0; kt < 4; ++kt) {
            f16x8 wt, ut;
            #pragma unroll
            for (int j = 0; j < 8; ++j) {
                const int krow = kt * 32 + lc * 8 + j;
                wt[j] = (f16)W[(size_t)krow * 512 + g * 128 + u];
                ut[j] = (f16)U[(size_t)krow * 512 + g * 128 + u];
            }
            Wf[g][kt] = wt;  Uf[g][kt] = ut;
        }
    }
    float bias[4];
    #pragma unroll
    for (int g = 0; g < 4; ++g) bias[g] = Bv[g * 128 + u];

    // ---- lane-constant addresses
    int ard[4];
    #pragma unroll
    for (int kt = 0; kt < 4; ++kt) ard[kt] = swb(lr, kt * 64 + lc * 16);
    const int wh_hi = swb(4 * lc + 1, u * 2);   // A1: h1 slot; A2: h2 slot
    const int wh_lo = swb(4 * lc,     u * 2);   // A2: h1 slot

    // ---- init: zero all tiles (pad rows stay zero forever); x[0] -> A1b[0]
    for (int i = tid; i < 4096; i += 512) {
        ((float*)A1b)[i] = 0.0f;
        ((float*)A2b)[i] = 0.0f;
    }
    __syncthreads();
    if (tid < 256) {
        const int a = tid >> 6, uc = (tid & 63) * 2;
        const float2 xv = *(const float2*)(X + (size_t)(b0 + a) * (T_STEPS * UNITS) + uc);
        *(unsigned*)(&A1b[0][0] + swb(4 * a, uc * 2)) = pkh(xv.x, xv.y);
    }
    __syncthreads();

    float c1 = 0.f, c2 = 0.f;

    for (int k = 0; k <= T_STEPS; ++k) {
        const int rdo = (k & 1) * TILEB, wro = TILEB - rdo;
        char* A1r = &A1b[0][0] + rdo;  char* A1w = &A1b[0][0] + wro;
        char* A2r = &A2b[0][0] + rdo;  char* A2w = &A2b[0][0] + wro;

        // x(k+1) prefetch (issued early; in flight under the MFMA phase)
        float xa = 0.f, xb = 0.f; int xrow = 0, xuc = 0;
        const bool ldx = (tid < 256) && (k + 1 < T_STEPS);
        if (ldx) {
            const int a = tid >> 6; xuc = (tid & 63) * 2; xrow = 4 * a;
            const float2 xv = *(const float2*)(X + (size_t)(b0 + a) * (T_STEPS * UNITS)
                                                 + (size_t)(k + 1) * UNITS + xuc);
            xa = xv.x; xb = xv.y;
        }

        // ---- A fragments from LDS
        f16x8 A1[4], A2[4];
        #pragma unroll
        for (int kt = 0; kt < 4; ++kt) {
            A1[kt] = *(const f16x8*)(A1r + ard[kt]);
            A2[kt] = *(const f16x8*)(A2r + ard[kt]);
        }

        // ---- P1: g,o chains (16 MFMA, ILP2)
        f32x4 accg = {bias[2], bias[2], bias[2], bias[2]};
        f32x4 acco = {bias[3], bias[3], bias[3], bias[3]};
        #pragma unroll
        for (int kt = 0; kt < 4; ++kt) {
            accg = MFMA16(A1[kt], Wf[2][kt], accg);
            acco = MFMA16(A1[kt], Wf[3][kt], acco);
        }
        #pragma unroll
        for (int kt = 0; kt < 4; ++kt) {
            accg = MFMA16(A2[kt], Uf[2][kt], accg);
            acco = MFMA16(A2[kt], Uf[3][kt], acco);
        }

        // ---- P2: i,f chains with g/o trans + x-write spliced (dep-free)
        f32x4 acci = {bias[0], bias[0], bias[0], bias[0]};
        f32x4 accf = {bias[1], bias[1], bias[1], bias[1]};
        float gg0, gg1, oo0, oo1;
        acci = MFMA16(A1[0], Wf[0][0], acci);  accf = MFMA16(A1[0], Wf[1][0], accf);
        gg0 = tanhf_(accg[0]);
        acci = MFMA16(A1[1], Wf[0][1], acci);  accf = MFMA16(A1[1], Wf[1][1], accf);
        oo0 = sigmoidf_(acco[0]);
        acci = MFMA16(A1[2], Wf[0][2], acci);  accf = MFMA16(A1[2], Wf[1][2], accf);
        gg1 = tanhf_(accg[1]);
        acci = MFMA16(A1[3], Wf[0][3], acci);  accf = MFMA16(A1[3], Wf[1][3], accf);
        oo1 = sigmoidf_(acco[1]);
        acci = MFMA16(A2[0], Uf[0][0], acci);  accf = MFMA16(A2[0], Uf[1][0], accf);
        if (ldx)  // x(k+1) -> A1 write tile, row 4a
            *(unsigned*)(A1w + swb(xrow, xuc * 2)) = pkh(xa, xb);
        acci = MFMA16(A2[1], Uf[0][1], acci);  accf = MFMA16(A2[1], Uf[1][1], accf);
        acci = MFMA16(A2[2], Uf[0][2], acci);  accf = MFMA16(A2[2], Uf[1][2], accf);
        acci = MFMA16(A2[3], Uf[0][3], acci);  accf = MFMA16(A2[3], Uf[1][3], accf);

        // ---- tail: e=0 (cell1 step k), e=1 (cell2 step k-1), interleaved
        const bool act1 = (k < T_STEPS);
        const bool act2 = (k > 0);
        const float si0 = sigmoidf_(acci[0]);
        const float si1 = sigmoidf_(acci[1]);
        const float sf0 = sigmoidf_(accf[0]);
        const float sf1 = sigmoidf_(accf[1]);
        const float gg1b = tanhf_(accg[1] * 0.0f + accg[1]);  // keep accg[1] path simple
        (void)gg1b;
        const float cn1 = sf0 * c1 + si0 * gg0;
        const float cn2 = sf1 * c2 + si1 * gg1;
        if (act1) c1 = cn1;
        if (act2) c2 = cn2;
        const float h1v = oo0 * tanhf_(cn1);
        const float h2v = oo1 * tanhf_(cn2);

        // ---- h writes to write tiles
        if (act1) {
            *(f16*)(A1w + wh_hi) = (f16)h1v;   // h1 -> A1 row 4lc+1
            *(f16*)(A2w + wh_lo) = (f16)h1v;   // h1 -> A2 row 4lc
        }
        if (act2 && k < T_STEPS)
            *(f16*)(A2w + wh_hi) = (f16)h2v;   // h2 -> A2 row 4lc+1

        // ---- final outputs
        if (k == T_STEPS - 1)
            out[OUT_C1 + (size_t)(b0 + lc) * UNITS + u] = c1;
        if (k == T_STEPS)
            out[(size_t)(b0 + lc) * UNITS + u] = h2v;
        __syncthreads();
    }
}

extern "C" void kernel_launch(void* const* d_in, const int* in_sizes, int n_in,
                              void* d_out, int out_size, void* d_ws, size_t ws_size,
                              hipStream_t stream) {
    const float* X  = (const float*)d_in[0];
    const float* W  = (const float*)d_in[1];
    const float* U  = (const float*)d_in[2];
    const float* Bv = (const float*)d_in[3];
    float* out = (float*)d_out;
    hipLaunchKernelGGL(lstm2_kernel, dim3(NBLK), dim3(512), 0, stream,
                       X, W, U, Bv, out);
}